// Round 7
// baseline (483.224 us; speedup 1.0000x reference)
//
#include <hip/hip_runtime.h>
#include <stdint.h>

#define L_SEQ   2048
#define BATCH   8
#define DMODEL  512
#define DINNER  1024
#define NHEADS  16
#define HEADDIM 64
#define DSTATE  16
#define CONVDIM 1056
#define DINPROJ 2096
#define NPROJ   4192          // 2*DINPROJ
#define NPROJ_P 4224          // padded to 33*128 for guard-free B staging
#define NROWS   (BATCH*L_SEQ) // 16384
#define NCH     32            // scan chunks (32 -> 16 waves/CU for latency hiding)
#define CHLEN   64            // L_SEQ/NCH
#define XBCW    1072          // xBC (1056) + dt (16) columns, bf16 buffer width

typedef __attribute__((ext_vector_type(8))) short short8;
typedef __attribute__((ext_vector_type(4))) float f32x4;

static __device__ __forceinline__ unsigned short f2bf(float f) {
    unsigned int u = __float_as_uint(f);
    u += 0x7FFF + ((u >> 16) & 1);
    return (unsigned short)(u >> 16);
}
static __device__ __forceinline__ float bf2f(unsigned short u) {
    return __uint_as_float((unsigned int)u << 16);
}
static __device__ __forceinline__ float silu(float v) {
    return v / (1.f + __expf(-v));
}
// async global->LDS, 16 B per lane; lds base must be wave-uniform
static __device__ __forceinline__ void glds16(const unsigned short* g, unsigned short* l) {
    __builtin_amdgcn_global_load_lds(
        (const __attribute__((address_space(1))) unsigned int*)g,
        (__attribute__((address_space(3))) unsigned int*)l, 16, 0, 0);
}

// -------- merged prepack (vectorized; W2 pre-scaled by norm_w: W2'[n,k]=W2*nw[k]) ---
#define PREP_N1 (NROWS*DMODEL)        // 8388608
#define PREP_N2 (NPROJ_P*DMODEL)      // 2162688
#define PREP_N3 (512*2048)            // 1048576
#define PREP_T  ((PREP_N1+PREP_N2+PREP_N3)/4)
static __device__ __forceinline__ uint2 pack4(float4 v) {
    uint2 o;
    o.x = (unsigned int)f2bf(v.x) | ((unsigned int)f2bf(v.y) << 16);
    o.y = (unsigned int)f2bf(v.z) | ((unsigned int)f2bf(v.w) << 16);
    return o;
}
__global__ void k_prep(const float* __restrict__ x,
                       const float* __restrict__ fwi, const float* __restrict__ bwi,
                       const float* __restrict__ fow, const float* __restrict__ bow,
                       const float* __restrict__ fnw, const float* __restrict__ bnw,
                       unsigned short* __restrict__ XB, unsigned short* __restrict__ W1,
                       unsigned short* __restrict__ W2) {
    int i = blockIdx.x * 256 + threadIdx.x;
    if (i >= PREP_T) return;
    int j4 = i * 4;
    if (j4 < PREP_N1) {
        *(uint2*)&XB[j4] = pack4(*(const float4*)&x[j4]);
    } else if (j4 < PREP_N1 + PREP_N2) {
        int j = j4 - PREP_N1;
        const int FS = DINPROJ * DMODEL;
        uint2 o = {0u, 0u};
        if (j < 2 * FS)
            o = pack4(j < FS ? *(const float4*)&fwi[j] : *(const float4*)&bwi[j - FS]);
        *(uint2*)&W1[j] = o;
    } else {
        int j = j4 - PREP_N1 - PREP_N2;
        int n = j >> 11, k = j & 2047;        // k is 4-aligned; never crosses 1024
        float4 wv = (k < DINNER) ? *(const float4*)&fow[n * DINNER + k]
                                 : *(const float4*)&bow[n * DINNER + k - DINNER];
        float4 nv = (k < DINNER) ? *(const float4*)&fnw[k]
                                 : *(const float4*)&bnw[k - DINNER];
        wv.x *= nv.x; wv.y *= nv.y; wv.z *= nv.z; wv.w *= nv.w;
        *(uint2*)&W2[j] = pack4(wv);
    }
}

// ---------------- bf16 MFMA GEMM core: 128x128 tile (m97 structure) ----------------
// 4 waves, each owns a 64x64 quadrant: acc[4][4] f32x4 (64 AGPR), 16 MFMA +
// 8 ds_read_b128 + 4 global_load_lds per wave per K-round, 32 KB LDS dbuf,
// one barrier/round. LB2=4 on proj: 60 VGPR + 64 AGPR -> 4 blocks/CU (measured).
#define BM 128
#define BN 128
#define BK 32

#define GEMM_BODY(NROUNDS, EPILOGUE)                                                        \
    __shared__ __align__(16) unsigned short as[2][BM][BK];                                  \
    __shared__ __align__(16) unsigned short bs[2][BN][BK];                                  \
    const int tid = threadIdx.x;                                                            \
    const int lane = tid & 63;                                                              \
    const int wave = tid >> 6;                                                              \
    const int wm = (wave & 1) * 64;                                                         \
    const int wn = (wave >> 1) * 64;                                                        \
    const int l16 = lane & 15;                                                              \
    const int q = lane >> 4;                                                                \
    const int sr = wave * 32;                                                               \
    const int lr = lane >> 2;                                                               \
    const int lc = (lane & 3) * 8;                                                          \
    f32x4 acc[4][4];                                                                        \
    for (int i = 0; i < 4; i++)                                                             \
        for (int j = 0; j < 4; j++) acc[i][j] = (f32x4){0.f, 0.f, 0.f, 0.f};                \
    const unsigned short* Ab = A + (size_t)(bm + sr + lr) * K + koff + lc;                  \
    const unsigned short* Bb = Bw + (size_t)(bn + sr + lr) * K + koff + lc;                 \
    glds16(Ab, &as[0][sr][0]);                                                              \
    glds16(Ab + (size_t)16 * K, &as[0][sr + 16][0]);                                        \
    glds16(Bb, &bs[0][sr][0]);                                                              \
    glds16(Bb + (size_t)16 * K, &bs[0][sr + 16][0]);                                        \
    __syncthreads();                                                                        \
    for (int r = 0; r < NROUNDS; r++) {                                                     \
        const int pb = r & 1;                                                               \
        if (r + 1 < NROUNDS) {  /* stage next round BEFORE consuming current */             \
            const int kb = (r + 1) * BK;                                                    \
            glds16(Ab + kb, &as[pb ^ 1][sr][0]);                                            \
            glds16(Ab + (size_t)16 * K + kb, &as[pb ^ 1][sr + 16][0]);                      \
            glds16(Bb + kb, &bs[pb ^ 1][sr][0]);                                            \
            glds16(Bb + (size_t)16 * K + kb, &bs[pb ^ 1][sr + 16][0]);                      \
        }                                                                                   \
        short8 af[4], bfr[4];                                                               \
        for (int i = 0; i < 4; i++) af[i] = *(const short8*)&as[pb][wm + i * 16 + l16][q * 8]; \
        for (int j = 0; j < 4; j++) bfr[j] = *(const short8*)&bs[pb][wn + j * 16 + l16][q * 8]; \
        for (int i = 0; i < 4; i++)                                                         \
            for (int j = 0; j < 4; j++)                                                     \
                acc[i][j] = __builtin_amdgcn_mfma_f32_16x16x32_bf16(af[i], bfr[j], acc[i][j], 0, 0, 0); \
        __syncthreads();  /* vmcnt drain of stage(r+1) lands here */                        \
    }                                                                                       \
    EPILOGUE

// in_proj GEMM: XCD-swizzled 1D grid (8*16*33 = 4224 blocks), K=512 -> 16 rounds.
__global__ __launch_bounds__(256, 4) void k_gemm_proj(const unsigned short* __restrict__ A,
                                                      const unsigned short* __restrict__ Bw,
                                                      unsigned short* __restrict__ ZG,
                                                      unsigned short* __restrict__ XBCDT) {
    const int K = DMODEL;
    const int N = NPROJ;
    const int lin = blockIdx.x;
    const int xcd = lin & 7;
    const int idx = lin >> 3;
    const int mloc = idx & 15;
    const int n_tile = idx >> 4;        // 0..32
    const int bm = (mloc * 8 + xcd) * BM;
    const int bn = n_tile * BN;
    const int koff = 0;
    GEMM_BODY(16, {
        for (int i = 0; i < 4; i++) {
            int row0 = bm + wm + i * 16 + q * 4;
            for (int j = 0; j < 4; j++) {
                int col = bn + wn + j * 16 + l16;
                if (col < N) {
                    int dir = col >= DINPROJ;
                    int cc = col - dir * DINPROJ;
                    for (int r = 0; r < 4; r++) {
                        unsigned short v = f2bf(acc[i][j][r]);
                        size_t rowo = (size_t)(dir * NROWS + row0 + r);
                        if (cc < DINNER)
                            ZG[rowo * DINNER + cc] = v;
                        else
                            XBCDT[rowo * XBCW + (cc - DINNER)] = v;
                    }
                }
            }
        }
    })
}

// out_proj GEMM with folded RMSNorm: A = gated Y (bf16, per-dir), B = W2' (=W2*nw).
// Rounds 0..31 accumulate the fwd half into accA; at r==32 save->accF, rezero;
// epilogue: C = sf[row]*accF + sb[row]*accA  (sf/sb = rsqrt(SSQ/1024+eps)).
// 64x128 tile, 1024 blocks (4/CU), K=2048 -> 64 rounds.
__global__ __launch_bounds__(256) void k_gemm_out(const unsigned short* __restrict__ Y,
                                                  const unsigned short* __restrict__ Bw,
                                                  const float* __restrict__ SSQ,
                                                  float* __restrict__ C) {
    __shared__ __align__(16) unsigned short as[2][64][BK];
    __shared__ __align__(16) unsigned short bs[2][BN][BK];
    const int lin = blockIdx.x;
    const int xcd = lin & 7;
    const int idx = lin >> 3;
    const int mloc = idx & 31;
    const int n_tile = idx >> 5;        // 0..3
    const int bm = (mloc * 8 + xcd) * 64;
    const int bn = n_tile * BN;
    const int tid = threadIdx.x;
    const int lane = tid & 63;
    const int wave = tid >> 6;
    const int wm = (wave & 1) * 32;
    const int wn = (wave >> 1) * 64;
    const int l16 = lane & 15;
    const int q = lane >> 4;
    const int sra = wave * 16;
    const int srb = wave * 32;
    const int lr = lane >> 2;
    const int lc = (lane & 3) * 8;
    f32x4 accA[2][4], accF[2][4];
    for (int i = 0; i < 2; i++)
        for (int j = 0; j < 4; j++) {
            accA[i][j] = (f32x4){0.f, 0.f, 0.f, 0.f};
            accF[i][j] = (f32x4){0.f, 0.f, 0.f, 0.f};
        }
    // A: fwd half rows at Y[row*1024], bwd half at Y[NROWS*1024 + row*1024]
    const unsigned short* AF = Y + (size_t)(bm + sra + lr) * DINNER + lc;
    const unsigned short* AB = AF + (size_t)NROWS * DINNER;
    const unsigned short* Bb = Bw + (size_t)(bn + srb + lr) * 2048 + lc;
    glds16(AF, &as[0][sra][0]);
    glds16(Bb, &bs[0][srb][0]);
    glds16(Bb + (size_t)16 * 2048, &bs[0][srb + 16][0]);
    __syncthreads();
    for (int r = 0; r < 64; r++) {
        const int pb = r & 1;
        if (r + 1 < 64) {
            const int t = r + 1;
            const unsigned short* asrc = (t < 32) ? AF + t * BK : AB + (t - 32) * BK;
            const int kb = t * BK;
            glds16(asrc, &as[pb ^ 1][sra][0]);
            glds16(Bb + kb, &bs[pb ^ 1][srb][0]);
            glds16(Bb + (size_t)16 * 2048 + kb, &bs[pb ^ 1][srb + 16][0]);
        }
        if (r == 32) {  // fwd K-half complete: save and restart accumulator
            for (int i = 0; i < 2; i++)
                for (int j = 0; j < 4; j++) {
                    accF[i][j] = accA[i][j];
                    accA[i][j] = (f32x4){0.f, 0.f, 0.f, 0.f};
                }
        }
        short8 af[2], bfr[4];
        for (int i = 0; i < 2; i++) af[i] = *(const short8*)&as[pb][wm + i * 16 + l16][q * 8];
        for (int j = 0; j < 4; j++) bfr[j] = *(const short8*)&bs[pb][wn + j * 16 + l16][q * 8];
        for (int i = 0; i < 2; i++)
            for (int j = 0; j < 4; j++)
                accA[i][j] = __builtin_amdgcn_mfma_f32_16x16x32_bf16(af[i], bfr[j], accA[i][j], 0, 0, 0);
        __syncthreads();
    }
    for (int i = 0; i < 2; i++) {
        int row0 = bm + wm + i * 16 + q * 4;
        for (int r = 0; r < 4; r++) {
            int row = row0 + r;
            float sf = rsqrtf(SSQ[row] * (1.f / 1024.f) + 1e-5f);
            float sb = rsqrtf(SSQ[NROWS + row] * (1.f / 1024.f) + 1e-5f);
            for (int j = 0; j < 4; j++) {
                int col = bn + wn + j * 16 + l16;
                C[(size_t)row * 512 + col] = sf * accF[i][j][r] + sb * accA[i][j][r];
            }
        }
    }
}

// ---------------- LDS-tiled depthwise causal conv + silu (vectorized staging) -------
__global__ __launch_bounds__(256) void k_conv2(const unsigned short* __restrict__ XBCDT,
                                               const float* __restrict__ fw_w, const float* __restrict__ fw_b,
                                               const float* __restrict__ bw_w, const float* __restrict__ bw_b,
                                               unsigned short* __restrict__ XS, float* __restrict__ BCb) {
    __shared__ unsigned short sm[70][256];  // rows l0-3 .. l0+66
    int t = threadIdx.x;
    int bidx = blockIdx.x;
    int lcn = bidx & 31;
    int b   = (bidx >> 5) & 7;
    int dir = (bidx >> 8) & 1;
    int ct  = bidx >> 9;
    int c0 = ct * 256;
    int l0 = lcn * 64;
    int c = c0 + t;
    const unsigned short* src = XBCDT + (size_t)dir * NROWS * XBCW;
    // vectorized stage: thread t -> row group (t>>5), 16B chunk (t&31)
    {
        const int rr = t >> 5;          // 0..7
        const int ch = t & 31;          // 0..31
        const int cc0 = c0 + ch * 8;    // chunk start col
        const bool cok16 = (cc0 + 8 <= XBCW);   // fully inside buffer row
        const short8 z8 = {0, 0, 0, 0, 0, 0, 0, 0};
#pragma unroll
        for (int pass = 0; pass < 9; ++pass) {
            int r = pass * 8 + rr;
            if (r < 70) {
                int li = l0 - 3 + r;
                short8 v = z8;
                if (li >= 0 && li < L_SEQ && cok16)
                    v = *(const short8*)&src[(size_t)((b << 11) + li) * XBCW + cc0];
                *(short8*)&sm[r][ch * 8] = v;
            }
        }
    }
    __syncthreads();
    if (c >= CONVDIM) return;
    const float* w = (dir ? bw_w : fw_w) + c * 4;
    float bias = (dir ? bw_b : fw_b)[c];
    float wr[4];
    if (dir) { wr[0] = w[3]; wr[1] = w[2]; wr[2] = w[1]; wr[3] = w[0]; }
    else     { wr[0] = w[0]; wr[1] = w[1]; wr[2] = w[2]; wr[3] = w[3]; }
    int o = dir ? 3 : 0;
    float w0 = bf2f(sm[o][t]), w1 = bf2f(sm[o + 1][t]), w2 = bf2f(sm[o + 2][t]);
    unsigned short* xso = XS + (size_t)dir * NROWS * DINNER;
    float* bco = BCb + (size_t)dir * NROWS * 32;
    int rowbase = (b << 11) + l0;
#pragma unroll 4
    for (int l = 0; l < 64; l++) {
        float w3 = bf2f(sm[l + o + 3][t]);
        float acc = ((wr[0] * w0 + wr[1] * w1) + (wr[2] * w2 + wr[3] * w3)) + bias;
        float v = silu(acc);
        int row = rowbase + l;
        if (c < DINNER)
            xso[(size_t)row * DINNER + c] = f2bf(v);
        else
            bco[(size_t)row * 32 + (c - DINNER)] = v;
        w0 = w1; w1 = w2; w2 = w3;
    }
}

// ---------------- dt/dA precompute ----------------
__global__ void k_dt(const unsigned short* __restrict__ XBCDT,
                     const float* __restrict__ fdtb, const float* __restrict__ fAl,
                     const float* __restrict__ bdtb, const float* __restrict__ bAl,
                     float* __restrict__ DT, float* __restrict__ DA) {
    int gid = blockIdx.x * 256 + threadIdx.x;
    if (gid >= 2 * NROWS * NHEADS) return;
    int h = gid & 15;
    int row = (gid >> 4) & (NROWS - 1);
    int dir = gid >> 18;
    float dtb = (dir ? bdtb : fdtb)[h];
    float Al = (dir ? bAl : fAl)[h];
    float x = bf2f(XBCDT[(size_t)(dir * NROWS + row) * XBCW + CONVDIM + h]) + dtb;
    float dt = (x > 15.f) ? x : log1pf(__expf(x));
    float dA = __expf(-__expf(Al) * dt);
    DT[gid] = dt;
    DA[gid] = dA;
}

// -------- scan pass A: 2 heads/block, 2 p per lane (4B packed XS loads) ------------
__global__ __launch_bounds__(64) void k_scan_state(const unsigned short* __restrict__ XS,
                                                   const float* __restrict__ BCb,
                                                   const float* __restrict__ DT,
                                                   const float* __restrict__ DA,
                                                   float* __restrict__ S, float* __restrict__ P) {
    int idx = blockIdx.x;  // (((dir*8+b)*8+hp)*32+chunk), 4096 blocks
    int c = idx & 31, hp = (idx >> 5) & 7, b = (idx >> 8) & 7, dir = idx >> 11;
    int t = threadIdx.x;
    int h = hp * 2 + (t >> 5);          // lanes 0-31: head hp*2, lanes 32-63: hp*2+1
    int p0 = (t & 31) * 2;
    const unsigned short* xs = XS + (size_t)dir * NROWS * DINNER;
    const float* bc = BCb + (size_t)dir * NROWS * 32;
    const float* dtp = DT + (size_t)dir * NROWS * NHEADS;
    const float* dap = DA + (size_t)dir * NROWS * NHEADS;
    float hreg0[16], hreg1[16];
#pragma unroll
    for (int n = 0; n < 16; n++) { hreg0[n] = 0.f; hreg1[n] = 0.f; }
    float Pp = 1.f;
#pragma unroll 4
    for (int tl = 0; tl < CHLEN; ++tl) {
        int tt = c * CHLEN + tl;
        int l = dir ? (L_SEQ - 1 - tt) : tt;
        int row = (b << 11) + l;
        unsigned int xv2 = *(const unsigned int*)&xs[(size_t)row * DINNER + h * HEADDIM + p0];
        float xv0 = bf2f((unsigned short)(xv2 & 0xffff));
        float xv1 = bf2f((unsigned short)(xv2 >> 16));
        float dt = dtp[row * 16 + h];
        float dA = dap[row * 16 + h];
        f32x4 Bv[4];
#pragma unroll
        for (int qq = 0; qq < 4; qq++) Bv[qq] = *(const f32x4*)&bc[(size_t)row * 32 + qq * 4];
        float k0 = dt * xv0, k1 = dt * xv1;
#pragma unroll
        for (int n = 0; n < 16; n++) {
            float bv = Bv[n >> 2][n & 3];
            hreg0[n] = fmaf(hreg0[n], dA, k0 * bv);
            hreg1[n] = fmaf(hreg1[n], dA, k1 * bv);
        }
        Pp *= dA;
    }
    int sh = (((dir * 8 + b) * 16 + h) * NCH + c);   // S layout: [group][chunk][p][n]
#pragma unroll
    for (int qq = 0; qq < 4; qq++) {
        f32x4 v0 = {hreg0[qq * 4], hreg0[qq * 4 + 1], hreg0[qq * 4 + 2], hreg0[qq * 4 + 3]};
        f32x4 v1 = {hreg1[qq * 4], hreg1[qq * 4 + 1], hreg1[qq * 4 + 2], hreg1[qq * 4 + 3]};
        *(f32x4*)&S[(size_t)sh * 1024 + p0 * 16 + qq * 4] = v0;
        *(f32x4*)&S[(size_t)sh * 1024 + (p0 + 1) * 16 + qq * 4] = v1;
    }
    if ((t & 31) == 0) P[sh] = Pp;
}

// -------- scan pass B: combine chunk states IN PLACE (S -> Hinit); zero SSQ --------
__global__ void k_combine(float* __restrict__ S, const float* __restrict__ P,
                          float* __restrict__ SSQ) {
    int gid = blockIdx.x * 256 + threadIdx.x;  // 2*8*16*1024 = 262144
    if (gid < 2 * NROWS) SSQ[gid] = 0.f;       // zero row-ssq for fused gate pass
    if (gid >= 2 * 8 * 16 * 1024) return;
    int pn = gid & 1023;
    int base = gid >> 10;
    float H = 0.f;
#pragma unroll 4
    for (int c = 0; c < NCH; c++) {
        size_t o = ((size_t)base * NCH + c) * 1024 + pn;
        float s = S[o];   // read BEFORE overwrite
        S[o] = H;         // S becomes Hinit
        H = H * P[base * NCH + c] + s;
    }
}

// -- scan pass C: replay + fused silu(z) gating; writes gated v, accumulates row ssq --
__global__ __launch_bounds__(64) void k_scan_out(const unsigned short* __restrict__ XS,
                                                 const float* __restrict__ BCb,
                                                 const float* __restrict__ DT,
                                                 const float* __restrict__ DA,
                                                 const float* __restrict__ Hinit,
                                                 const float* __restrict__ fDp,
                                                 const float* __restrict__ bDp,
                                                 const unsigned short* __restrict__ ZG,
                                                 float* __restrict__ SSQ,
                                                 unsigned short* __restrict__ Y) {
    int idx = blockIdx.x;  // (((dir*8+b)*8+hp)*32+chunk), 4096 blocks
    int c = idx & 31, hp = (idx >> 5) & 7, b = (idx >> 8) & 7, dir = idx >> 11;
    int t = threadIdx.x;
    int h = hp * 2 + (t >> 5);
    int p0 = (t & 31) * 2;
    const unsigned short* xs = XS + (size_t)dir * NROWS * DINNER;
    const unsigned short* zgd = ZG + (size_t)dir * NROWS * DINNER;
    const float* bc = BCb + (size_t)dir * NROWS * 32;
    const float* dtp = DT + (size_t)dir * NROWS * NHEADS;
    const float* dap = DA + (size_t)dir * NROWS * NHEADS;
    unsigned short* yo = Y + (size_t)dir * NROWS * DINNER;
    float* ssqd = SSQ + (size_t)dir * NROWS;
    float Dpv = (dir ? bDp : fDp)[h];
    int sh = (((dir * 8 + b) * 16 + h) * NCH + c);
    float hreg0[16], hreg1[16];
#pragma unroll
    for (int qq = 0; qq < 4; qq++) {
        f32x4 v0 = *(const f32x4*)&Hinit[(size_t)sh * 1024 + p0 * 16 + qq * 4];
        f32x4 v1 = *(const f32x4*)&Hinit[(size_t)sh * 1024 + (p0 + 1) * 16 + qq * 4];
#pragma unroll
        for (int e = 0; e < 4; e++) { hreg0[qq * 4 + e] = v0[e]; hreg1[qq * 4 + e] = v1[e]; }
    }
#pragma unroll 4
    for (int tl = 0; tl < CHLEN; ++tl) {
        int tt = c * CHLEN + tl;
        int l = dir ? (L_SEQ - 1 - tt) : tt;
        int row = (b << 11) + l;
        unsigned int xv2 = *(const unsigned int*)&xs[(size_t)row * DINNER + h * HEADDIM + p0];
        float xv0 = bf2f((unsigned short)(xv2 & 0xffff));
        float xv1 = bf2f((unsigned short)(xv2 >> 16));
        float dt = dtp[row * 16 + h];
        float dA = dap[row * 16 + h];
        f32x4 Bv[4], Cv[4];
#pragma unroll
        for (int qq = 0; qq < 4; qq++) Bv[qq] = *(const f32x4*)&bc[(size_t)row * 32 + qq * 4];
#pragma unroll
        for (int qq = 0; qq < 4; qq++) Cv[qq] = *(const f32x4*)&bc[(size_t)row * 32 + 16 + qq * 4];
        float k0 = dt * xv0, k1 = dt * xv1;
        float y0 = 0.f, y1 = 0.f;
#pragma unroll
        for (int n = 0; n < 16; n++) {
            float bv = Bv[n >> 2][n & 3];
            float cv = Cv[n >> 2][n & 3];
            hreg0[n] = fmaf(hreg0[n], dA, k0 * bv);
            hreg1[n] = fmaf(hreg1[n], dA, k1 * bv);
            y0 = fmaf(hreg0[n], cv, y0);
            y1 = fmaf(hreg1[n], cv, y1);
        }
        // fused gate: v = (y + x*Dp) * silu(z)
        unsigned int zz = *(const unsigned int*)&zgd[(size_t)row * DINNER + h * HEADDIM + p0];
        float v0 = (y0 + xv0 * Dpv) * silu(bf2f((unsigned short)(zz & 0xffff)));
        float v1 = (y1 + xv1 * Dpv) * silu(bf2f((unsigned short)(zz >> 16)));
        unsigned int yw = (unsigned int)f2bf(v0) | ((unsigned int)f2bf(v1) << 16);
        *(unsigned int*)&yo[(size_t)row * DINNER + h * HEADDIM + p0] = yw;  // same 4B read above
        // per-row ssq partial: reduce 32 lanes of this half-wave, 1 atomic/row/half-wave
        float pr = v0 * v0 + v1 * v1;
#pragma unroll
        for (int off = 16; off > 0; off >>= 1) pr += __shfl_down(pr, off);
        if ((t & 31) == 0) atomicAdd(&ssqd[row], pr);
    }
}

// ---------------- host launch ----------------
extern "C" void kernel_launch(void* const* d_in, const int* in_sizes, int n_in,
                              void* d_out, int out_size, void* d_ws, size_t ws_size,
                              hipStream_t stream) {
    const float* x     = (const float*)d_in[0];
    const float* f_inw = (const float*)d_in[1];
    const float* f_cw  = (const float*)d_in[2];
    const float* f_cb  = (const float*)d_in[3];
    const float* f_dtb = (const float*)d_in[4];
    const float* f_Al  = (const float*)d_in[5];
    const float* f_Dp  = (const float*)d_in[6];
    const float* f_nw  = (const float*)d_in[7];
    const float* f_ow  = (const float*)d_in[8];
    const float* b_inw = (const float*)d_in[9];
    const float* b_cw  = (const float*)d_in[10];
    const float* b_cb  = (const float*)d_in[11];
    const float* b_dtb = (const float*)d_in[12];
    const float* b_Al  = (const float*)d_in[13];
    const float* b_Dp  = (const float*)d_in[14];
    const float* b_nw  = (const float*)d_in[15];
    const float* b_ow  = (const float*)d_in[16];

    char* ws = (char*)d_ws;
    size_t off = 0;
    auto alloc = [&](size_t bytes) {
        void* p = ws + off;
        off += (bytes + 255) & ~(size_t)255;
        return p;
    };
    // --- persistent-phase buffers ---
    // union: XBCDT (in_proj -> conv/dt) / {S,P} (phase 4; dead after scan_out)
    unsigned short* XBCDT = (unsigned short*)alloc((size_t)2 * NROWS * XBCW * 2);   // 70.3 MB
    float* S = (float*)XBCDT;       // 2*8*16*NCH*1024*4 = 33.6 MB
    float* P = (float*)((char*)XBCDT + (size_t)2 * 8 * 16 * NCH * 1024 * 4);  // 32 KB
    // union: XS (conv -> scans) / Y (scan C writes over XS element-after-read;
    //        Y then feeds out-GEMM directly — norm folded into W2' + epilogue scale)
    unsigned short* XS    = (unsigned short*)alloc((size_t)2 * NROWS * DINNER * 2); // 67.1 MB
    unsigned short* Yb    = XS;
    unsigned short* ZG    = (unsigned short*)alloc((size_t)2 * NROWS * DINNER * 2); // 67.1 MB
    unsigned short* W2    = (unsigned short*)alloc((size_t)512 * 2048 * 2);         //  2.1 MB
    float* BCb  = (float*)alloc((size_t)2 * NROWS * 32 * 4);                        //  4.2 MB
    float* DT   = (float*)alloc((size_t)2 * NROWS * NHEADS * 4);                    //  2.1 MB
    float* DA   = (float*)alloc((size_t)2 * NROWS * NHEADS * 4);                    //  2.1 MB
    float* SSQ  = (float*)alloc((size_t)2 * NROWS * 4);                             //  0.1 MB
    // union: {XB, W1} (phase 0-1 only)
    char* unionBase = (char*)alloc((size_t)16777216 + (size_t)NPROJ_P * DMODEL * 2); // 21.1 MB
    unsigned short* XB = (unsigned short*)unionBase;
    unsigned short* W1 = (unsigned short*)(unionBase + 16777216);
    // total: ~236 MB

    if (ws_size < off) return;  // defensive: fail cleanly (wrong answer) instead of faulting

    // 1. merged prepack (vectorized; W2' = W2 * norm_w folded)
    k_prep<<<(PREP_T + 255) / 256, 256, 0, stream>>>(x, f_inw, b_inw, f_ow, b_ow,
                                                     f_nw, b_nw, XB, W1, W2);
    // 2. in_proj GEMM (both dirs), XCD-swizzled 128x128 pipelined, routed bf16 epilogue
    k_gemm_proj<<<8 * 16 * 33, 256, 0, stream>>>(XB, W1, ZG, XBCDT);
    // 3. LDS-tiled conv + dt prep
    k_conv2<<<5 * 2 * 8 * 32, 256, 0, stream>>>(XBCDT, f_cw, f_cb, b_cw, b_cb, XS, BCb);
    {
        int n = 2 * NROWS * NHEADS;
        k_dt<<<(n + 255) / 256, 256, 0, stream>>>(XBCDT, f_dtb, f_Al, b_dtb, b_Al, DT, DA);
    }
    // 4. chunked scan, NCH=32 (S/P written over dead XBCDT region; combine in-place)
    k_scan_state<<<2 * 8 * 8 * NCH, 64, 0, stream>>>(XS, BCb, DT, DA, S, P);
    {
        int n = 2 * 8 * 16 * 1024;
        k_combine<<<(n + 255) / 256, 256, 0, stream>>>(S, P, SSQ);
    }
    k_scan_out<<<2 * 8 * 8 * NCH, 64, 0, stream>>>(XS, BCb, DT, DA, S, f_Dp, b_Dp, ZG, SSQ, Yb);
    // 5. out_proj GEMM reads gated Y directly; per-dir accumulators scaled by
    //    rsqrt(SSQ) in the epilogue (gatenorm kernel eliminated) -> d_out
    k_gemm_out<<<8 * 32 * 4, 256, 0, stream>>>(Yb, W2, SSQ, (float*)d_out);
}

// Round 8
// 459.144 us; speedup vs baseline: 1.0524x; 1.0524x over previous
//
#include <hip/hip_runtime.h>
#include <stdint.h>

#define L_SEQ   2048
#define BATCH   8
#define DMODEL  512
#define DINNER  1024
#define NHEADS  16
#define HEADDIM 64
#define DSTATE  16
#define CONVDIM 1056
#define DINPROJ 2096
#define NPROJ   4192          // 2*DINPROJ
#define NPROJ_P 4224          // padded to 33*128 for guard-free B staging
#define NROWS   (BATCH*L_SEQ) // 16384
#define NCH     32            // scan chunks (32 -> 16 waves/CU for latency hiding)
#define CHLEN   64            // L_SEQ/NCH
#define XBCW    1072          // xBC (1056) + dt (16) columns, bf16 buffer width

typedef __attribute__((ext_vector_type(8))) short short8;
typedef __attribute__((ext_vector_type(4))) float f32x4;

static __device__ __forceinline__ unsigned short f2bf(float f) {
    unsigned int u = __float_as_uint(f);
    u += 0x7FFF + ((u >> 16) & 1);
    return (unsigned short)(u >> 16);
}
static __device__ __forceinline__ float bf2f(unsigned short u) {
    return __uint_as_float((unsigned int)u << 16);
}
static __device__ __forceinline__ float silu(float v) {
    return v / (1.f + __expf(-v));
}
// async global->LDS, 16 B per lane; lds base must be wave-uniform
static __device__ __forceinline__ void glds16(const unsigned short* g, unsigned short* l) {
    __builtin_amdgcn_global_load_lds(
        (const __attribute__((address_space(1))) unsigned int*)g,
        (__attribute__((address_space(3))) unsigned int*)l, 16, 0, 0);
}

// -------- merged prepack (vectorized: 4 elems/thread, float4 in, uint2 out) --------
#define PREP_N1 (NROWS*DMODEL)        // 8388608
#define PREP_N2 (NPROJ_P*DMODEL)      // 2162688
#define PREP_N3 (512*2048)            // 1048576
#define PREP_T  ((PREP_N1+PREP_N2+PREP_N3)/4)
static __device__ __forceinline__ uint2 pack4(float4 v) {
    uint2 o;
    o.x = (unsigned int)f2bf(v.x) | ((unsigned int)f2bf(v.y) << 16);
    o.y = (unsigned int)f2bf(v.z) | ((unsigned int)f2bf(v.w) << 16);
    return o;
}
__global__ void k_prep(const float* __restrict__ x,
                       const float* __restrict__ fwi, const float* __restrict__ bwi,
                       const float* __restrict__ fow, const float* __restrict__ bow,
                       unsigned short* __restrict__ XB, unsigned short* __restrict__ W1,
                       unsigned short* __restrict__ W2) {
    int i = blockIdx.x * 256 + threadIdx.x;
    if (i >= PREP_T) return;
    int j4 = i * 4;
    if (j4 < PREP_N1) {
        *(uint2*)&XB[j4] = pack4(*(const float4*)&x[j4]);
    } else if (j4 < PREP_N1 + PREP_N2) {
        int j = j4 - PREP_N1;
        const int FS = DINPROJ * DMODEL;   // FS and 2*FS are 4-aligned: no straddle
        uint2 o = {0u, 0u};
        if (j < 2 * FS)
            o = pack4(j < FS ? *(const float4*)&fwi[j] : *(const float4*)&bwi[j - FS]);
        *(uint2*)&W1[j] = o;
    } else {
        int j = j4 - PREP_N1 - PREP_N2;
        int n = j >> 11, k = j & 2047;     // k 4-aligned, never crosses 1024
        const float* s = (k < DINNER) ? &fow[n * DINNER + k] : &bow[n * DINNER + k - DINNER];
        *(uint2*)&W2[j] = pack4(*(const float4*)s);
    }
}

// ---------------- bf16 MFMA GEMM core: 128x128 tile (m97 structure) ----------------
// 4 waves, each owns a 64x64 quadrant: acc[4][4] f32x4 (64 AGPR), 16 MFMA +
// 8 ds_read_b128 + 4 global_load_lds per wave per K-round, 32 KB LDS dbuf,
// one barrier/round. LB2=4: 60 VGPR + 64 AGPR -> 4 blocks/CU (measured on proj:
// occupancy 30->38%, dur -9%, no spill).
#define BM 128
#define BN 128
#define BK 32

#define GEMM_BODY(NROUNDS, EPILOGUE)                                                        \
    __shared__ __align__(16) unsigned short as[2][BM][BK];                                  \
    __shared__ __align__(16) unsigned short bs[2][BN][BK];                                  \
    const int tid = threadIdx.x;                                                            \
    const int lane = tid & 63;                                                              \
    const int wave = tid >> 6;                                                              \
    const int wm = (wave & 1) * 64;                                                         \
    const int wn = (wave >> 1) * 64;                                                        \
    const int l16 = lane & 15;                                                              \
    const int q = lane >> 4;                                                                \
    const int sr = wave * 32;                                                               \
    const int lr = lane >> 2;                                                               \
    const int lc = (lane & 3) * 8;                                                          \
    f32x4 acc[4][4];                                                                        \
    for (int i = 0; i < 4; i++)                                                             \
        for (int j = 0; j < 4; j++) acc[i][j] = (f32x4){0.f, 0.f, 0.f, 0.f};                \
    const unsigned short* Ab = A + (size_t)(bm + sr + lr) * K + koff + lc;                  \
    const unsigned short* Bb = Bw + (size_t)(bn + sr + lr) * K + koff + lc;                 \
    glds16(Ab, &as[0][sr][0]);                                                              \
    glds16(Ab + (size_t)16 * K, &as[0][sr + 16][0]);                                        \
    glds16(Bb, &bs[0][sr][0]);                                                              \
    glds16(Bb + (size_t)16 * K, &bs[0][sr + 16][0]);                                        \
    __syncthreads();                                                                        \
    for (int r = 0; r < NROUNDS; r++) {                                                     \
        const int pb = r & 1;                                                               \
        if (r + 1 < NROUNDS) {  /* stage next round BEFORE consuming current */             \
            const int kb = (r + 1) * BK;                                                    \
            glds16(Ab + kb, &as[pb ^ 1][sr][0]);                                            \
            glds16(Ab + (size_t)16 * K + kb, &as[pb ^ 1][sr + 16][0]);                      \
            glds16(Bb + kb, &bs[pb ^ 1][sr][0]);                                            \
            glds16(Bb + (size_t)16 * K + kb, &bs[pb ^ 1][sr + 16][0]);                      \
        }                                                                                   \
        short8 af[4], bfr[4];                                                               \
        for (int i = 0; i < 4; i++) af[i] = *(const short8*)&as[pb][wm + i * 16 + l16][q * 8]; \
        for (int j = 0; j < 4; j++) bfr[j] = *(const short8*)&bs[pb][wn + j * 16 + l16][q * 8]; \
        for (int i = 0; i < 4; i++)                                                         \
            for (int j = 0; j < 4; j++)                                                     \
                acc[i][j] = __builtin_amdgcn_mfma_f32_16x16x32_bf16(af[i], bfr[j], acc[i][j], 0, 0, 0); \
        __syncthreads();  /* vmcnt drain of stage(r+1) lands here */                        \
    }                                                                                       \
    EPILOGUE

// in_proj GEMM: XCD-swizzled 1D grid (8*16*33 = 4224 blocks), K=512 -> 16 rounds.
__global__ __launch_bounds__(256, 4) void k_gemm_proj(const unsigned short* __restrict__ A,
                                                      const unsigned short* __restrict__ Bw,
                                                      unsigned short* __restrict__ ZG,
                                                      unsigned short* __restrict__ XBCDT) {
    const int K = DMODEL;
    const int N = NPROJ;
    const int lin = blockIdx.x;
    const int xcd = lin & 7;
    const int idx = lin >> 3;
    const int mloc = idx & 15;
    const int n_tile = idx >> 4;        // 0..32
    const int bm = (mloc * 8 + xcd) * BM;
    const int bn = n_tile * BN;
    const int koff = 0;
    GEMM_BODY(16, {
        for (int i = 0; i < 4; i++) {
            int row0 = bm + wm + i * 16 + q * 4;
            for (int j = 0; j < 4; j++) {
                int col = bn + wn + j * 16 + l16;
                if (col < N) {
                    int dir = col >= DINPROJ;
                    int cc = col - dir * DINPROJ;
                    for (int r = 0; r < 4; r++) {
                        unsigned short v = f2bf(acc[i][j][r]);
                        size_t rowo = (size_t)(dir * NROWS + row0 + r);
                        if (cc < DINNER)
                            ZG[rowo * DINNER + cc] = v;
                        else
                            XBCDT[rowo * XBCW + (cc - DINNER)] = v;
                    }
                }
            }
        }
    })
}

// out_proj GEMM: XCD-swizzled (8*16*4 = 512 blocks), K=2048 -> 64 rounds.
// LB2=4 (proven on the identical body at proj): more resident blocks overlap drains.
__global__ __launch_bounds__(256, 4) void k_gemm_out(const unsigned short* __restrict__ A,
                                                     const unsigned short* __restrict__ Bw,
                                                     float* __restrict__ C) {
    const int K = 2048;
    const int lin = blockIdx.x;
    const int xcd = lin & 7;
    const int idx = lin >> 3;
    const int mloc = idx & 15;
    const int n_tile = idx >> 4;        // 0..3
    const int bm = (mloc * 8 + xcd) * BM;
    const int bn = n_tile * BN;
    const int koff = 0;
    GEMM_BODY(64, {
        for (int i = 0; i < 4; i++) {
            int row0 = bm + wm + i * 16 + q * 4;
            for (int j = 0; j < 4; j++) {
                int col = bn + wn + j * 16 + l16;
                for (int r = 0; r < 4; r++)
                    C[(size_t)(row0 + r) * 512 + col] = acc[i][j][r];
            }
        }
    })
}

// ---------------- LDS-tiled depthwise causal conv + silu (vectorized staging) -------
__global__ __launch_bounds__(256) void k_conv2(const unsigned short* __restrict__ XBCDT,
                                               const float* __restrict__ fw_w, const float* __restrict__ fw_b,
                                               const float* __restrict__ bw_w, const float* __restrict__ bw_b,
                                               unsigned short* __restrict__ XS, float* __restrict__ BCb) {
    __shared__ unsigned short sm[70][256];  // rows l0-3 .. l0+66
    int t = threadIdx.x;
    int bidx = blockIdx.x;
    int lcn = bidx & 31;
    int b   = (bidx >> 5) & 7;
    int dir = (bidx >> 8) & 1;
    int ct  = bidx >> 9;
    int c0 = ct * 256;
    int l0 = lcn * 64;
    int c = c0 + t;
    const unsigned short* src = XBCDT + (size_t)dir * NROWS * XBCW;
    // vectorized stage: thread t -> row group (t>>5), 16B chunk (t&31)
    {
        const int rr = t >> 5;          // 0..7
        const int ch = t & 31;          // 0..31
        const int cc0 = c0 + ch * 8;    // chunk start col
        const bool cok16 = (cc0 + 8 <= XBCW);   // fully inside buffer row
        const short8 z8 = {0, 0, 0, 0, 0, 0, 0, 0};
#pragma unroll
        for (int pass = 0; pass < 9; ++pass) {
            int r = pass * 8 + rr;
            if (r < 70) {
                int li = l0 - 3 + r;
                short8 v = z8;
                if (li >= 0 && li < L_SEQ && cok16)
                    v = *(const short8*)&src[(size_t)((b << 11) + li) * XBCW + cc0];
                *(short8*)&sm[r][ch * 8] = v;
            }
        }
    }
    __syncthreads();
    if (c >= CONVDIM) return;
    const float* w = (dir ? bw_w : fw_w) + c * 4;
    float bias = (dir ? bw_b : fw_b)[c];
    float wr[4];
    if (dir) { wr[0] = w[3]; wr[1] = w[2]; wr[2] = w[1]; wr[3] = w[0]; }
    else     { wr[0] = w[0]; wr[1] = w[1]; wr[2] = w[2]; wr[3] = w[3]; }
    int o = dir ? 3 : 0;
    float w0 = bf2f(sm[o][t]), w1 = bf2f(sm[o + 1][t]), w2 = bf2f(sm[o + 2][t]);
    unsigned short* xso = XS + (size_t)dir * NROWS * DINNER;
    float* bco = BCb + (size_t)dir * NROWS * 32;
    int rowbase = (b << 11) + l0;
#pragma unroll 4
    for (int l = 0; l < 64; l++) {
        float w3 = bf2f(sm[l + o + 3][t]);
        float acc = ((wr[0] * w0 + wr[1] * w1) + (wr[2] * w2 + wr[3] * w3)) + bias;
        float v = silu(acc);
        int row = rowbase + l;
        if (c < DINNER)
            xso[(size_t)row * DINNER + c] = f2bf(v);
        else
            bco[(size_t)row * 32 + (c - DINNER)] = v;
        w0 = w1; w1 = w2; w2 = w3;
    }
}

// ---------------- dt/dA precompute ----------------
__global__ void k_dt(const unsigned short* __restrict__ XBCDT,
                     const float* __restrict__ fdtb, const float* __restrict__ fAl,
                     const float* __restrict__ bdtb, const float* __restrict__ bAl,
                     float* __restrict__ DT, float* __restrict__ DA) {
    int gid = blockIdx.x * 256 + threadIdx.x;
    if (gid >= 2 * NROWS * NHEADS) return;
    int h = gid & 15;
    int row = (gid >> 4) & (NROWS - 1);
    int dir = gid >> 18;
    float dtb = (dir ? bdtb : fdtb)[h];
    float Al = (dir ? bAl : fAl)[h];
    float x = bf2f(XBCDT[(size_t)(dir * NROWS + row) * XBCW + CONVDIM + h]) + dtb;
    float dt = (x > 15.f) ? x : log1pf(__expf(x));
    float dA = __expf(-__expf(Al) * dt);
    DT[gid] = dt;
    DA[gid] = dA;
}

// -------- scan pass A: 2 heads/block, 2 p per lane (4B packed XS loads) ------------
__global__ __launch_bounds__(64) void k_scan_state(const unsigned short* __restrict__ XS,
                                                   const float* __restrict__ BCb,
                                                   const float* __restrict__ DT,
                                                   const float* __restrict__ DA,
                                                   float* __restrict__ S, float* __restrict__ P) {
    int idx = blockIdx.x;  // (((dir*8+b)*8+hp)*32+chunk), 4096 blocks
    int c = idx & 31, hp = (idx >> 5) & 7, b = (idx >> 8) & 7, dir = idx >> 11;
    int t = threadIdx.x;
    int h = hp * 2 + (t >> 5);          // lanes 0-31: head hp*2, lanes 32-63: hp*2+1
    int p0 = (t & 31) * 2;
    const unsigned short* xs = XS + (size_t)dir * NROWS * DINNER;
    const float* bc = BCb + (size_t)dir * NROWS * 32;
    const float* dtp = DT + (size_t)dir * NROWS * NHEADS;
    const float* dap = DA + (size_t)dir * NROWS * NHEADS;
    float hreg0[16], hreg1[16];
#pragma unroll
    for (int n = 0; n < 16; n++) { hreg0[n] = 0.f; hreg1[n] = 0.f; }
    float Pp = 1.f;
#pragma unroll 4
    for (int tl = 0; tl < CHLEN; ++tl) {
        int tt = c * CHLEN + tl;
        int l = dir ? (L_SEQ - 1 - tt) : tt;
        int row = (b << 11) + l;
        unsigned int xv2 = *(const unsigned int*)&xs[(size_t)row * DINNER + h * HEADDIM + p0];
        float xv0 = bf2f((unsigned short)(xv2 & 0xffff));
        float xv1 = bf2f((unsigned short)(xv2 >> 16));
        float dt = dtp[row * 16 + h];
        float dA = dap[row * 16 + h];
        f32x4 Bv[4];
#pragma unroll
        for (int qq = 0; qq < 4; qq++) Bv[qq] = *(const f32x4*)&bc[(size_t)row * 32 + qq * 4];
        float k0 = dt * xv0, k1 = dt * xv1;
#pragma unroll
        for (int n = 0; n < 16; n++) {
            float bv = Bv[n >> 2][n & 3];
            hreg0[n] = fmaf(hreg0[n], dA, k0 * bv);
            hreg1[n] = fmaf(hreg1[n], dA, k1 * bv);
        }
        Pp *= dA;
    }
    int sh = (((dir * 8 + b) * 16 + h) * NCH + c);   // S layout: [group][chunk][p][n]
#pragma unroll
    for (int qq = 0; qq < 4; qq++) {
        f32x4 v0 = {hreg0[qq * 4], hreg0[qq * 4 + 1], hreg0[qq * 4 + 2], hreg0[qq * 4 + 3]};
        f32x4 v1 = {hreg1[qq * 4], hreg1[qq * 4 + 1], hreg1[qq * 4 + 2], hreg1[qq * 4 + 3]};
        *(f32x4*)&S[(size_t)sh * 1024 + p0 * 16 + qq * 4] = v0;
        *(f32x4*)&S[(size_t)sh * 1024 + (p0 + 1) * 16 + qq * 4] = v1;
    }
    if ((t & 31) == 0) P[sh] = Pp;
}

// ---------------- scan pass B: combine chunk states IN PLACE (S -> Hinit) --------
__global__ void k_combine(float* __restrict__ S, const float* __restrict__ P) {
    int gid = blockIdx.x * 256 + threadIdx.x;  // 2*8*16*1024 = 262144
    if (gid >= 2 * 8 * 16 * 1024) return;
    int pn = gid & 1023;
    int base = gid >> 10;
    float H = 0.f;
#pragma unroll 4
    for (int c = 0; c < NCH; c++) {
        size_t o = ((size_t)base * NCH + c) * 1024 + pn;
        float s = S[o];   // read BEFORE overwrite
        S[o] = H;         // S becomes Hinit
        H = H * P[base * NCH + c] + s;
    }
}

// -------- scan pass C: 2 heads/block, 2 p per lane, packed 4B Y writes -------------
__global__ __launch_bounds__(64) void k_scan_out(const unsigned short* __restrict__ XS,
                                                 const float* __restrict__ BCb,
                                                 const float* __restrict__ DT,
                                                 const float* __restrict__ DA,
                                                 const float* __restrict__ Hinit,
                                                 const float* __restrict__ fDp,
                                                 const float* __restrict__ bDp,
                                                 unsigned short* __restrict__ Y) {
    int idx = blockIdx.x;  // (((dir*8+b)*8+hp)*32+chunk), 4096 blocks
    int c = idx & 31, hp = (idx >> 5) & 7, b = (idx >> 8) & 7, dir = idx >> 11;
    int t = threadIdx.x;
    int h = hp * 2 + (t >> 5);
    int p0 = (t & 31) * 2;
    const unsigned short* xs = XS + (size_t)dir * NROWS * DINNER;
    const float* bc = BCb + (size_t)dir * NROWS * 32;
    const float* dtp = DT + (size_t)dir * NROWS * NHEADS;
    const float* dap = DA + (size_t)dir * NROWS * NHEADS;
    unsigned short* yo = Y + (size_t)dir * NROWS * DINNER;
    float Dpv = (dir ? bDp : fDp)[h];
    int sh = (((dir * 8 + b) * 16 + h) * NCH + c);
    float hreg0[16], hreg1[16];
#pragma unroll
    for (int qq = 0; qq < 4; qq++) {
        f32x4 v0 = *(const f32x4*)&Hinit[(size_t)sh * 1024 + p0 * 16 + qq * 4];
        f32x4 v1 = *(const f32x4*)&Hinit[(size_t)sh * 1024 + (p0 + 1) * 16 + qq * 4];
#pragma unroll
        for (int e = 0; e < 4; e++) { hreg0[qq * 4 + e] = v0[e]; hreg1[qq * 4 + e] = v1[e]; }
    }
#pragma unroll 4
    for (int tl = 0; tl < CHLEN; ++tl) {
        int tt = c * CHLEN + tl;
        int l = dir ? (L_SEQ - 1 - tt) : tt;
        int row = (b << 11) + l;
        unsigned int xv2 = *(const unsigned int*)&xs[(size_t)row * DINNER + h * HEADDIM + p0];
        float xv0 = bf2f((unsigned short)(xv2 & 0xffff));
        float xv1 = bf2f((unsigned short)(xv2 >> 16));
        float dt = dtp[row * 16 + h];
        float dA = dap[row * 16 + h];
        f32x4 Bv[4], Cv[4];
#pragma unroll
        for (int qq = 0; qq < 4; qq++) Bv[qq] = *(const f32x4*)&bc[(size_t)row * 32 + qq * 4];
#pragma unroll
        for (int qq = 0; qq < 4; qq++) Cv[qq] = *(const f32x4*)&bc[(size_t)row * 32 + 16 + qq * 4];
        float k0 = dt * xv0, k1 = dt * xv1;
        float y0 = 0.f, y1 = 0.f;
#pragma unroll
        for (int n = 0; n < 16; n++) {
            float bv = Bv[n >> 2][n & 3];
            float cv = Cv[n >> 2][n & 3];
            hreg0[n] = fmaf(hreg0[n], dA, k0 * bv);
            hreg1[n] = fmaf(hreg1[n], dA, k1 * bv);
            y0 = fmaf(hreg0[n], cv, y0);
            y1 = fmaf(hreg1[n], cv, y1);
        }
        unsigned int yw = (unsigned int)f2bf(y0 + xv0 * Dpv)
                        | ((unsigned int)f2bf(y1 + xv1 * Dpv) << 16);
        *(unsigned int*)&yo[(size_t)row * DINNER + h * HEADDIM + p0] = yw;  // same 4B read above
    }
}

// ---------------- gated RMSNorm -> bf16 concat (2 rows/block, 16B loads) -----------
__global__ __launch_bounds__(256) void k_gatenorm(const unsigned short* __restrict__ Y,
                                                  const unsigned short* __restrict__ ZG,
                                                  const float* __restrict__ fnw,
                                                  const float* __restrict__ bnw,
                                                  unsigned short* __restrict__ NRM) {
    int bid = blockIdx.x;           // 0..16383
    int t = threadIdx.x;
    int sub = t >> 7;               // which of 2 rows
    int tt = t & 127;
    int rid = bid * 2 + sub;        // 0..32767
    int dir = rid >> 14;
    int row = rid & (NROWS - 1);
    int c = tt * 8;
    const size_t base = (size_t)(dir * NROWS + row) * DINNER + c;
    uint4 yu = *(const uint4*)&Y[base];
    uint4 zu = *(const uint4*)&ZG[base];
    float v[8];
    {
        const unsigned int yw[4] = {yu.x, yu.y, yu.z, yu.w};
        const unsigned int zw[4] = {zu.x, zu.y, zu.z, zu.w};
#pragma unroll
        for (int e = 0; e < 4; e++) {
            v[e * 2]     = bf2f((unsigned short)(yw[e] & 0xffff)) * silu(bf2f((unsigned short)(zw[e] & 0xffff)));
            v[e * 2 + 1] = bf2f((unsigned short)(yw[e] >> 16))    * silu(bf2f((unsigned short)(zw[e] >> 16)));
        }
    }
    float ss = 0.f;
#pragma unroll
    for (int e = 0; e < 8; e++) ss += v[e] * v[e];
#pragma unroll
    for (int off = 32; off > 0; off >>= 1) ss += __shfl_down(ss, off);
    __shared__ float red[4];
    if ((t & 63) == 0) red[t >> 6] = ss;
    __syncthreads();
    float tot = red[sub * 2] + red[sub * 2 + 1];
    float scale = rsqrtf(tot * (1.f / 1024.f) + 1e-5f);
    const float* nw = (dir ? bnw : fnw) + c;
    f32x4 nw0 = *(const f32x4*)&nw[0];
    f32x4 nw1 = *(const f32x4*)&nw[4];
    unsigned int ow[4];
#pragma unroll
    for (int e = 0; e < 4; e++) {
        float a = v[e * 2]     * scale * (e < 2 ? nw0[e * 2]     : nw1[(e - 2) * 2]);
        float b = v[e * 2 + 1] * scale * (e < 2 ? nw0[e * 2 + 1] : nw1[(e - 2) * 2 + 1]);
        ow[e] = (unsigned int)f2bf(a) | ((unsigned int)f2bf(b) << 16);
    }
    uint4 o = {ow[0], ow[1], ow[2], ow[3]};
    *(uint4*)&NRM[(size_t)row * 2048 + dir * DINNER + c] = o;
}

// ---------------- host launch ----------------
extern "C" void kernel_launch(void* const* d_in, const int* in_sizes, int n_in,
                              void* d_out, int out_size, void* d_ws, size_t ws_size,
                              hipStream_t stream) {
    const float* x     = (const float*)d_in[0];
    const float* f_inw = (const float*)d_in[1];
    const float* f_cw  = (const float*)d_in[2];
    const float* f_cb  = (const float*)d_in[3];
    const float* f_dtb = (const float*)d_in[4];
    const float* f_Al  = (const float*)d_in[5];
    const float* f_Dp  = (const float*)d_in[6];
    const float* f_nw  = (const float*)d_in[7];
    const float* f_ow  = (const float*)d_in[8];
    const float* b_inw = (const float*)d_in[9];
    const float* b_cw  = (const float*)d_in[10];
    const float* b_cb  = (const float*)d_in[11];
    const float* b_dtb = (const float*)d_in[12];
    const float* b_Al  = (const float*)d_in[13];
    const float* b_Dp  = (const float*)d_in[14];
    const float* b_nw  = (const float*)d_in[15];
    const float* b_ow  = (const float*)d_in[16];

    char* ws = (char*)d_ws;
    size_t off = 0;
    auto alloc = [&](size_t bytes) {
        void* p = ws + off;
        off += (bytes + 255) & ~(size_t)255;
        return p;
    };
    // --- persistent-phase buffers ---
    // union: XBCDT (in_proj -> conv/dt) / {S,P} (phase 4) / NRM (gatenorm -> out GEMM)
    // XBCDT dead after k_dt; S+P (33.6 MB) alive only during phase 4; NRM written
    // phase 5 after scan_out consumed S. All stream-ordered, disjoint lifetimes.
    unsigned short* XBCDT = (unsigned short*)alloc((size_t)2 * NROWS * XBCW * 2);   // 70.3 MB
    unsigned short* NRM   = XBCDT;  // 67.1 MB <= 70.3 MB
    float* S = (float*)XBCDT;       // 2*8*16*NCH*1024*4 = 33.6 MB
    float* P = (float*)((char*)XBCDT + (size_t)2 * 8 * 16 * NCH * 1024 * 4);  // 32 KB
    // union: XS (conv -> scans) / Y (scan C writes over XS element-after-read)
    unsigned short* XS    = (unsigned short*)alloc((size_t)2 * NROWS * DINNER * 2); // 67.1 MB
    unsigned short* Yb    = XS;
    unsigned short* ZG    = (unsigned short*)alloc((size_t)2 * NROWS * DINNER * 2); // 67.1 MB
    unsigned short* W2    = (unsigned short*)alloc((size_t)512 * 2048 * 2);         //  2.1 MB
    float* BCb  = (float*)alloc((size_t)2 * NROWS * 32 * 4);                        //  4.2 MB
    float* DT   = (float*)alloc((size_t)2 * NROWS * NHEADS * 4);                    //  2.1 MB
    float* DA   = (float*)alloc((size_t)2 * NROWS * NHEADS * 4);                    //  2.1 MB
    // union: {XB, W1} (phase 0-1 only)
    char* unionBase = (char*)alloc((size_t)16777216 + (size_t)NPROJ_P * DMODEL * 2); // 21.1 MB
    unsigned short* XB = (unsigned short*)unionBase;
    unsigned short* W1 = (unsigned short*)(unionBase + 16777216);
    // total: ~236 MB

    if (ws_size < off) return;  // defensive: fail cleanly (wrong answer) instead of faulting

    // 1. merged prepack (vectorized)
    k_prep<<<(PREP_T + 255) / 256, 256, 0, stream>>>(x, f_inw, b_inw, f_ow, b_ow, XB, W1, W2);
    // 2. in_proj GEMM (both dirs), XCD-swizzled 128x128 pipelined, routed bf16 epilogue
    k_gemm_proj<<<8 * 16 * 33, 256, 0, stream>>>(XB, W1, ZG, XBCDT);
    // 3. LDS-tiled conv + dt prep
    k_conv2<<<5 * 2 * 8 * 32, 256, 0, stream>>>(XBCDT, f_cw, f_cb, b_cw, b_cb, XS, BCb);
    {
        int n = 2 * NROWS * NHEADS;
        k_dt<<<(n + 255) / 256, 256, 0, stream>>>(XBCDT, f_dtb, f_Al, b_dtb, b_Al, DT, DA);
    }
    // 4. chunked scan, NCH=32 (S/P written over dead XBCDT region; combine in-place)
    k_scan_state<<<2 * 8 * 8 * NCH, 64, 0, stream>>>(XS, BCb, DT, DA, S, P);
    {
        int n = 2 * 8 * 16 * 1024;
        k_combine<<<(n + 255) / 256, 256, 0, stream>>>(S, P);
    }
    k_scan_out<<<2 * 8 * 8 * NCH, 64, 0, stream>>>(XS, BCb, DT, DA, S, f_Dp, b_Dp, Yb);
    // 5. gated RMSNorm -> bf16 (writes NRM over dead XBCDT/S region)
    k_gatenorm<<<NROWS, 256, 0, stream>>>(Yb, ZG, f_nw, b_nw, NRM);
    // 6. out_proj GEMM (both dirs summed via K-concat), XCD-swizzled -> d_out
    k_gemm_out<<<8 * 16 * 4, 256, 0, stream>>>(NRM, W2, (float*)d_out);
}

// Round 9
// 458.398 us; speedup vs baseline: 1.0542x; 1.0016x over previous
//
#include <hip/hip_runtime.h>
#include <stdint.h>

#define L_SEQ   2048
#define BATCH   8
#define DMODEL  512
#define DINNER  1024
#define NHEADS  16
#define HEADDIM 64
#define DSTATE  16
#define CONVDIM 1056
#define DINPROJ 2096
#define NPROJ   4192          // 2*DINPROJ
#define NPROJ_P 4224          // padded to 33*128 for guard-free B staging
#define NROWS   (BATCH*L_SEQ) // 16384
#define NCH     32            // scan chunks (32 -> 16 waves/CU for latency hiding)
#define CHLEN   64            // L_SEQ/NCH
#define XBCW    1072          // xBC (1056) + dt (16) columns, bf16 buffer width

typedef __attribute__((ext_vector_type(8))) short short8;
typedef __attribute__((ext_vector_type(4))) float f32x4;

static __device__ __forceinline__ unsigned short f2bf(float f) {
    unsigned int u = __float_as_uint(f);
    u += 0x7FFF + ((u >> 16) & 1);
    return (unsigned short)(u >> 16);
}
static __device__ __forceinline__ float bf2f(unsigned short u) {
    return __uint_as_float((unsigned int)u << 16);
}
static __device__ __forceinline__ float silu(float v) {
    return v / (1.f + __expf(-v));
}
// async global->LDS, 16 B per lane; lds base must be wave-uniform
static __device__ __forceinline__ void glds16(const unsigned short* g, unsigned short* l) {
    __builtin_amdgcn_global_load_lds(
        (const __attribute__((address_space(1))) unsigned int*)g,
        (__attribute__((address_space(3))) unsigned int*)l, 16, 0, 0);
}
// raw barrier (no waitcnt drain) wrapped in compiler memory fences
#define BARX() do { asm volatile("" ::: "memory"); __builtin_amdgcn_s_barrier(); \
                    asm volatile("" ::: "memory"); } while (0)
// counted vmem wait (memory-clobber keeps ds/vmem ops from crossing)
#define WAITV(n) asm volatile("s_waitcnt vmcnt(" #n ")" ::: "memory")

// -------- merged prepack (vectorized: 4 elems/thread, float4 in, uint2 out) --------
#define PREP_N1 (NROWS*DMODEL)        // 8388608
#define PREP_N2 (NPROJ_P*DMODEL)      // 2162688
#define PREP_N3 (512*2048)            // 1048576
#define PREP_T  ((PREP_N1+PREP_N2+PREP_N3)/4)
static __device__ __forceinline__ uint2 pack4(float4 v) {
    uint2 o;
    o.x = (unsigned int)f2bf(v.x) | ((unsigned int)f2bf(v.y) << 16);
    o.y = (unsigned int)f2bf(v.z) | ((unsigned int)f2bf(v.w) << 16);
    return o;
}
__global__ void k_prep(const float* __restrict__ x,
                       const float* __restrict__ fwi, const float* __restrict__ bwi,
                       const float* __restrict__ fow, const float* __restrict__ bow,
                       unsigned short* __restrict__ XB, unsigned short* __restrict__ W1,
                       unsigned short* __restrict__ W2) {
    int i = blockIdx.x * 256 + threadIdx.x;
    if (i >= PREP_T) return;
    int j4 = i * 4;
    if (j4 < PREP_N1) {
        *(uint2*)&XB[j4] = pack4(*(const float4*)&x[j4]);
    } else if (j4 < PREP_N1 + PREP_N2) {
        int j = j4 - PREP_N1;
        const int FS = DINPROJ * DMODEL;   // FS and 2*FS are 4-aligned: no straddle
        uint2 o = {0u, 0u};
        if (j < 2 * FS)
            o = pack4(j < FS ? *(const float4*)&fwi[j] : *(const float4*)&bwi[j - FS]);
        *(uint2*)&W1[j] = o;
    } else {
        int j = j4 - PREP_N1 - PREP_N2;
        int n = j >> 11, k = j & 2047;     // k 4-aligned, never crosses 1024
        const float* s = (k < DINNER) ? &fow[n * DINNER + k] : &bow[n * DINNER + k - DINNER];
        *(uint2*)&W2[j] = pack4(*(const float4*)s);
    }
}

#define BM 128
#define BN 128
#define BK 32

// ---- in_proj GEMM: 128x128 tile, TRIPLE-buffered LDS + counted vmcnt (T4) --------
// Same geometry/staging/epilogue as the proven 2-phase body; only the sync skeleton
// differs: stage K-tile r+2 each round, steady-state s_waitcnt vmcnt(8) (8 loads in
// flight across both raw s_barriers), vmcnt(0) only on the final round.
// Ledger: prologue STAGE(0)+STAGE(1)=8; per round +4 (STAGE(r+2)), drain to 8
// retires exactly STAGE(r); tail r=14: WAITV(4); r=15: WAITV(0).
// Slot safety: write slot (r+2)%3 != read slot r%3 != next slot (r+1)%3; reads of
// slot (r-1)%3 = (r+2)%3 completed before prior round's MFMAs -> before top barrier.
// LDS 48 KB -> 3 blocks/CU (pipeline replaces the lost TLP).
__global__ __launch_bounds__(256, 4) void k_gemm_proj(const unsigned short* __restrict__ A,
                                                      const unsigned short* __restrict__ Bw,
                                                      unsigned short* __restrict__ ZG,
                                                      unsigned short* __restrict__ XBCDT) {
    __shared__ __align__(16) unsigned short as[3][BM][BK];
    __shared__ __align__(16) unsigned short bs[3][BN][BK];
    const int K = DMODEL;               // 16 rounds
    const int N = NPROJ;
    const int lin = blockIdx.x;
    const int xcd = lin & 7;
    const int idx = lin >> 3;
    const int mloc = idx & 15;
    const int n_tile = idx >> 4;        // 0..32
    const int bm = (mloc * 8 + xcd) * BM;
    const int bn = n_tile * BN;
    const int tid = threadIdx.x;
    const int lane = tid & 63;
    const int wave = tid >> 6;
    const int wm = (wave & 1) * 64;
    const int wn = (wave >> 1) * 64;
    const int l16 = lane & 15;
    const int q = lane >> 4;
    const int sr = wave * 32;
    const int lr = lane >> 2;
    const int lc = (lane & 3) * 8;
    f32x4 acc[4][4];
#pragma unroll
    for (int i = 0; i < 4; i++)
#pragma unroll
        for (int j = 0; j < 4; j++) acc[i][j] = (f32x4){0.f, 0.f, 0.f, 0.f};
    const unsigned short* Ab = A + (size_t)(bm + sr + lr) * K + lc;
    const unsigned short* Bb = Bw + (size_t)(bn + sr + lr) * K + lc;
    auto STAGE = [&](int t) {
        const int s = t % 3;
        const int kb = t * BK;
        glds16(Ab + kb, &as[s][sr][0]);
        glds16(Ab + (size_t)16 * K + kb, &as[s][sr + 16][0]);
        glds16(Bb + kb, &bs[s][sr][0]);
        glds16(Bb + (size_t)16 * K + kb, &bs[s][sr + 16][0]);
    };
    STAGE(0);
    STAGE(1);
    for (int r = 0; r < 16; ++r) {
        if (r) BARX();                  // reads of slot (r+2)%3 (done in r-1) drained
        if (r + 2 < 16) STAGE(r + 2);   // keep 2 tiles in flight
        if (r + 2 < 16)      WAITV(8);  // retire STAGE(r); newer 8 stay in flight
        else if (r + 1 < 16) WAITV(4);
        else                 WAITV(0);
        BARX();                         // publish slot r
        const int pb = r % 3;
        short8 af[4], bfr[4];
#pragma unroll
        for (int i = 0; i < 4; i++) af[i] = *(const short8*)&as[pb][wm + i * 16 + l16][q * 8];
#pragma unroll
        for (int j = 0; j < 4; j++) bfr[j] = *(const short8*)&bs[pb][wn + j * 16 + l16][q * 8];
        __builtin_amdgcn_s_setprio(1);
#pragma unroll
        for (int i = 0; i < 4; i++)
#pragma unroll
            for (int j = 0; j < 4; j++)
                acc[i][j] = __builtin_amdgcn_mfma_f32_16x16x32_bf16(af[i], bfr[j], acc[i][j], 0, 0, 0);
        __builtin_amdgcn_s_setprio(0);
    }
    // routed bf16 epilogue (unchanged)
#pragma unroll
    for (int i = 0; i < 4; i++) {
        int row0 = bm + wm + i * 16 + q * 4;
#pragma unroll
        for (int j = 0; j < 4; j++) {
            int col = bn + wn + j * 16 + l16;
            if (col < N) {
                int dir = col >= DINPROJ;
                int cc = col - dir * DINPROJ;
#pragma unroll
                for (int r = 0; r < 4; r++) {
                    unsigned short v = f2bf(acc[i][j][r]);
                    size_t rowo = (size_t)(dir * NROWS + row0 + r);
                    if (cc < DINNER)
                        ZG[rowo * DINNER + cc] = v;
                    else
                        XBCDT[rowo * XBCW + (cc - DINNER)] = v;
                }
            }
        }
    }
}

// ---------------- 2-phase GEMM body (known-good) for out_proj ----------------------
#define GEMM_BODY(NROUNDS, EPILOGUE)                                                        \
    __shared__ __align__(16) unsigned short as[2][BM][BK];                                  \
    __shared__ __align__(16) unsigned short bs[2][BN][BK];                                  \
    const int tid = threadIdx.x;                                                            \
    const int lane = tid & 63;                                                              \
    const int wave = tid >> 6;                                                              \
    const int wm = (wave & 1) * 64;                                                         \
    const int wn = (wave >> 1) * 64;                                                        \
    const int l16 = lane & 15;                                                              \
    const int q = lane >> 4;                                                                \
    const int sr = wave * 32;                                                               \
    const int lr = lane >> 2;                                                               \
    const int lc = (lane & 3) * 8;                                                          \
    f32x4 acc[4][4];                                                                        \
    for (int i = 0; i < 4; i++)                                                             \
        for (int j = 0; j < 4; j++) acc[i][j] = (f32x4){0.f, 0.f, 0.f, 0.f};                \
    const unsigned short* Ab = A + (size_t)(bm + sr + lr) * K + koff + lc;                  \
    const unsigned short* Bb = Bw + (size_t)(bn + sr + lr) * K + koff + lc;                 \
    glds16(Ab, &as[0][sr][0]);                                                              \
    glds16(Ab + (size_t)16 * K, &as[0][sr + 16][0]);                                        \
    glds16(Bb, &bs[0][sr][0]);                                                              \
    glds16(Bb + (size_t)16 * K, &bs[0][sr + 16][0]);                                        \
    __syncthreads();                                                                        \
    for (int r = 0; r < NROUNDS; r++) {                                                     \
        const int pb = r & 1;                                                               \
        if (r + 1 < NROUNDS) {  /* stage next round BEFORE consuming current */             \
            const int kb = (r + 1) * BK;                                                    \
            glds16(Ab + kb, &as[pb ^ 1][sr][0]);                                            \
            glds16(Ab + (size_t)16 * K + kb, &as[pb ^ 1][sr + 16][0]);                      \
            glds16(Bb + kb, &bs[pb ^ 1][sr][0]);                                            \
            glds16(Bb + (size_t)16 * K + kb, &bs[pb ^ 1][sr + 16][0]);                      \
        }                                                                                   \
        short8 af[4], bfr[4];                                                               \
        for (int i = 0; i < 4; i++) af[i] = *(const short8*)&as[pb][wm + i * 16 + l16][q * 8]; \
        for (int j = 0; j < 4; j++) bfr[j] = *(const short8*)&bs[pb][wn + j * 16 + l16][q * 8]; \
        for (int i = 0; i < 4; i++)                                                         \
            for (int j = 0; j < 4; j++)                                                     \
                acc[i][j] = __builtin_amdgcn_mfma_f32_16x16x32_bf16(af[i], bfr[j], acc[i][j], 0, 0, 0); \
        __syncthreads();  /* vmcnt drain of stage(r+1) lands here */                        \
    }                                                                                       \
    EPILOGUE

// out_proj GEMM: XCD-swizzled (8*16*4 = 512 blocks), K=2048 -> 64 rounds, LB2=4.
__global__ __launch_bounds__(256, 4) void k_gemm_out(const unsigned short* __restrict__ A,
                                                     const unsigned short* __restrict__ Bw,
                                                     float* __restrict__ C) {
    const int K = 2048;
    const int lin = blockIdx.x;
    const int xcd = lin & 7;
    const int idx = lin >> 3;
    const int mloc = idx & 15;
    const int n_tile = idx >> 4;        // 0..3
    const int bm = (mloc * 8 + xcd) * BM;
    const int bn = n_tile * BN;
    const int koff = 0;
    GEMM_BODY(64, {
        for (int i = 0; i < 4; i++) {
            int row0 = bm + wm + i * 16 + q * 4;
            for (int j = 0; j < 4; j++) {
                int col = bn + wn + j * 16 + l16;
                for (int r = 0; r < 4; r++)
                    C[(size_t)(row0 + r) * 512 + col] = acc[i][j][r];
            }
        }
    })
}

// ---------------- LDS-tiled depthwise causal conv + silu (vectorized staging) -------
__global__ __launch_bounds__(256) void k_conv2(const unsigned short* __restrict__ XBCDT,
                                               const float* __restrict__ fw_w, const float* __restrict__ fw_b,
                                               const float* __restrict__ bw_w, const float* __restrict__ bw_b,
                                               unsigned short* __restrict__ XS, float* __restrict__ BCb) {
    __shared__ unsigned short sm[70][256];  // rows l0-3 .. l0+66
    int t = threadIdx.x;
    int bidx = blockIdx.x;
    int lcn = bidx & 31;
    int b   = (bidx >> 5) & 7;
    int dir = (bidx >> 8) & 1;
    int ct  = bidx >> 9;
    int c0 = ct * 256;
    int l0 = lcn * 64;
    int c = c0 + t;
    const unsigned short* src = XBCDT + (size_t)dir * NROWS * XBCW;
    // vectorized stage: thread t -> row group (t>>5), 16B chunk (t&31)
    {
        const int rr = t >> 5;          // 0..7
        const int ch = t & 31;          // 0..31
        const int cc0 = c0 + ch * 8;    // chunk start col
        const bool cok16 = (cc0 + 8 <= XBCW);   // fully inside buffer row
        const short8 z8 = {0, 0, 0, 0, 0, 0, 0, 0};
#pragma unroll
        for (int pass = 0; pass < 9; ++pass) {
            int r = pass * 8 + rr;
            if (r < 70) {
                int li = l0 - 3 + r;
                short8 v = z8;
                if (li >= 0 && li < L_SEQ && cok16)
                    v = *(const short8*)&src[(size_t)((b << 11) + li) * XBCW + cc0];
                *(short8*)&sm[r][ch * 8] = v;
            }
        }
    }
    __syncthreads();
    if (c >= CONVDIM) return;
    const float* w = (dir ? bw_w : fw_w) + c * 4;
    float bias = (dir ? bw_b : fw_b)[c];
    float wr[4];
    if (dir) { wr[0] = w[3]; wr[1] = w[2]; wr[2] = w[1]; wr[3] = w[0]; }
    else     { wr[0] = w[0]; wr[1] = w[1]; wr[2] = w[2]; wr[3] = w[3]; }
    int o = dir ? 3 : 0;
    float w0 = bf2f(sm[o][t]), w1 = bf2f(sm[o + 1][t]), w2 = bf2f(sm[o + 2][t]);
    unsigned short* xso = XS + (size_t)dir * NROWS * DINNER;
    float* bco = BCb + (size_t)dir * NROWS * 32;
    int rowbase = (b << 11) + l0;
#pragma unroll 4
    for (int l = 0; l < 64; l++) {
        float w3 = bf2f(sm[l + o + 3][t]);
        float acc = ((wr[0] * w0 + wr[1] * w1) + (wr[2] * w2 + wr[3] * w3)) + bias;
        float v = silu(acc);
        int row = rowbase + l;
        if (c < DINNER)
            xso[(size_t)row * DINNER + c] = f2bf(v);
        else
            bco[(size_t)row * 32 + (c - DINNER)] = v;
        w0 = w1; w1 = w2; w2 = w3;
    }
}

// ---------------- dt/dA precompute ----------------
__global__ void k_dt(const unsigned short* __restrict__ XBCDT,
                     const float* __restrict__ fdtb, const float* __restrict__ fAl,
                     const float* __restrict__ bdtb, const float* __restrict__ bAl,
                     float* __restrict__ DT, float* __restrict__ DA) {
    int gid = blockIdx.x * 256 + threadIdx.x;
    if (gid >= 2 * NROWS * NHEADS) return;
    int h = gid & 15;
    int row = (gid >> 4) & (NROWS - 1);
    int dir = gid >> 18;
    float dtb = (dir ? bdtb : fdtb)[h];
    float Al = (dir ? bAl : fAl)[h];
    float x = bf2f(XBCDT[(size_t)(dir * NROWS + row) * XBCW + CONVDIM + h]) + dtb;
    float dt = (x > 15.f) ? x : log1pf(__expf(x));
    float dA = __expf(-__expf(Al) * dt);
    DT[gid] = dt;
    DA[gid] = dA;
}

// -------- scan pass A: 2 heads/block, 2 p per lane (4B packed XS loads) ------------
__global__ __launch_bounds__(64) void k_scan_state(const unsigned short* __restrict__ XS,
                                                   const float* __restrict__ BCb,
                                                   const float* __restrict__ DT,
                                                   const float* __restrict__ DA,
                                                   float* __restrict__ S, float* __restrict__ P) {
    int idx = blockIdx.x;  // (((dir*8+b)*8+hp)*32+chunk), 4096 blocks
    int c = idx & 31, hp = (idx >> 5) & 7, b = (idx >> 8) & 7, dir = idx >> 11;
    int t = threadIdx.x;
    int h = hp * 2 + (t >> 5);          // lanes 0-31: head hp*2, lanes 32-63: hp*2+1
    int p0 = (t & 31) * 2;
    const unsigned short* xs = XS + (size_t)dir * NROWS * DINNER;
    const float* bc = BCb + (size_t)dir * NROWS * 32;
    const float* dtp = DT + (size_t)dir * NROWS * NHEADS;
    const float* dap = DA + (size_t)dir * NROWS * NHEADS;
    float hreg0[16], hreg1[16];
#pragma unroll
    for (int n = 0; n < 16; n++) { hreg0[n] = 0.f; hreg1[n] = 0.f; }
    float Pp = 1.f;
#pragma unroll 4
    for (int tl = 0; tl < CHLEN; ++tl) {
        int tt = c * CHLEN + tl;
        int l = dir ? (L_SEQ - 1 - tt) : tt;
        int row = (b << 11) + l;
        unsigned int xv2 = *(const unsigned int*)&xs[(size_t)row * DINNER + h * HEADDIM + p0];
        float xv0 = bf2f((unsigned short)(xv2 & 0xffff));
        float xv1 = bf2f((unsigned short)(xv2 >> 16));
        float dt = dtp[row * 16 + h];
        float dA = dap[row * 16 + h];
        f32x4 Bv[4];
#pragma unroll
        for (int qq = 0; qq < 4; qq++) Bv[qq] = *(const f32x4*)&bc[(size_t)row * 32 + qq * 4];
        float k0 = dt * xv0, k1 = dt * xv1;
#pragma unroll
        for (int n = 0; n < 16; n++) {
            float bv = Bv[n >> 2][n & 3];
            hreg0[n] = fmaf(hreg0[n], dA, k0 * bv);
            hreg1[n] = fmaf(hreg1[n], dA, k1 * bv);
        }
        Pp *= dA;
    }
    int sh = (((dir * 8 + b) * 16 + h) * NCH + c);   // S layout: [group][chunk][p][n]
#pragma unroll
    for (int qq = 0; qq < 4; qq++) {
        f32x4 v0 = {hreg0[qq * 4], hreg0[qq * 4 + 1], hreg0[qq * 4 + 2], hreg0[qq * 4 + 3]};
        f32x4 v1 = {hreg1[qq * 4], hreg1[qq * 4 + 1], hreg1[qq * 4 + 2], hreg1[qq * 4 + 3]};
        *(f32x4*)&S[(size_t)sh * 1024 + p0 * 16 + qq * 4] = v0;
        *(f32x4*)&S[(size_t)sh * 1024 + (p0 + 1) * 16 + qq * 4] = v1;
    }
    if ((t & 31) == 0) P[sh] = Pp;
}

// ---------------- scan pass B: combine chunk states IN PLACE (S -> Hinit) --------
__global__ void k_combine(float* __restrict__ S, const float* __restrict__ P) {
    int gid = blockIdx.x * 256 + threadIdx.x;  // 2*8*16*1024 = 262144
    if (gid >= 2 * 8 * 16 * 1024) return;
    int pn = gid & 1023;
    int base = gid >> 10;
    float H = 0.f;
#pragma unroll 4
    for (int c = 0; c < NCH; c++) {
        size_t o = ((size_t)base * NCH + c) * 1024 + pn;
        float s = S[o];   // read BEFORE overwrite
        S[o] = H;         // S becomes Hinit
        H = H * P[base * NCH + c] + s;
    }
}

// -------- scan pass C: 2 heads/block, 2 p per lane, packed 4B Y writes -------------
__global__ __launch_bounds__(64) void k_scan_out(const unsigned short* __restrict__ XS,
                                                 const float* __restrict__ BCb,
                                                 const float* __restrict__ DT,
                                                 const float* __restrict__ DA,
                                                 const float* __restrict__ Hinit,
                                                 const float* __restrict__ fDp,
                                                 const float* __restrict__ bDp,
                                                 unsigned short* __restrict__ Y) {
    int idx = blockIdx.x;  // (((dir*8+b)*8+hp)*32+chunk), 4096 blocks
    int c = idx & 31, hp = (idx >> 5) & 7, b = (idx >> 8) & 7, dir = idx >> 11;
    int t = threadIdx.x;
    int h = hp * 2 + (t >> 5);
    int p0 = (t & 31) * 2;
    const unsigned short* xs = XS + (size_t)dir * NROWS * DINNER;
    const float* bc = BCb + (size_t)dir * NROWS * 32;
    const float* dtp = DT + (size_t)dir * NROWS * NHEADS;
    const float* dap = DA + (size_t)dir * NROWS * NHEADS;
    unsigned short* yo = Y + (size_t)dir * NROWS * DINNER;
    float Dpv = (dir ? bDp : fDp)[h];
    int sh = (((dir * 8 + b) * 16 + h) * NCH + c);
    float hreg0[16], hreg1[16];
#pragma unroll
    for (int qq = 0; qq < 4; qq++) {
        f32x4 v0 = *(const f32x4*)&Hinit[(size_t)sh * 1024 + p0 * 16 + qq * 4];
        f32x4 v1 = *(const f32x4*)&Hinit[(size_t)sh * 1024 + (p0 + 1) * 16 + qq * 4];
#pragma unroll
        for (int e = 0; e < 4; e++) { hreg0[qq * 4 + e] = v0[e]; hreg1[qq * 4 + e] = v1[e]; }
    }
#pragma unroll 4
    for (int tl = 0; tl < CHLEN; ++tl) {
        int tt = c * CHLEN + tl;
        int l = dir ? (L_SEQ - 1 - tt) : tt;
        int row = (b << 11) + l;
        unsigned int xv2 = *(const unsigned int*)&xs[(size_t)row * DINNER + h * HEADDIM + p0];
        float xv0 = bf2f((unsigned short)(xv2 & 0xffff));
        float xv1 = bf2f((unsigned short)(xv2 >> 16));
        float dt = dtp[row * 16 + h];
        float dA = dap[row * 16 + h];
        f32x4 Bv[4], Cv[4];
#pragma unroll
        for (int qq = 0; qq < 4; qq++) Bv[qq] = *(const f32x4*)&bc[(size_t)row * 32 + qq * 4];
#pragma unroll
        for (int qq = 0; qq < 4; qq++) Cv[qq] = *(const f32x4*)&bc[(size_t)row * 32 + 16 + qq * 4];
        float k0 = dt * xv0, k1 = dt * xv1;
        float y0 = 0.f, y1 = 0.f;
#pragma unroll
        for (int n = 0; n < 16; n++) {
            float bv = Bv[n >> 2][n & 3];
            float cv = Cv[n >> 2][n & 3];
            hreg0[n] = fmaf(hreg0[n], dA, k0 * bv);
            hreg1[n] = fmaf(hreg1[n], dA, k1 * bv);
            y0 = fmaf(hreg0[n], cv, y0);
            y1 = fmaf(hreg1[n], cv, y1);
        }
        unsigned int yw = (unsigned int)f2bf(y0 + xv0 * Dpv)
                        | ((unsigned int)f2bf(y1 + xv1 * Dpv) << 16);
        *(unsigned int*)&yo[(size_t)row * DINNER + h * HEADDIM + p0] = yw;  // same 4B read above
    }
}

// ---------------- gated RMSNorm -> bf16 concat (2 rows/block, 16B loads) -----------
__global__ __launch_bounds__(256) void k_gatenorm(const unsigned short* __restrict__ Y,
                                                  const unsigned short* __restrict__ ZG,
                                                  const float* __restrict__ fnw,
                                                  const float* __restrict__ bnw,
                                                  unsigned short* __restrict__ NRM) {
    int bid = blockIdx.x;           // 0..16383
    int t = threadIdx.x;
    int sub = t >> 7;               // which of 2 rows
    int tt = t & 127;
    int rid = bid * 2 + sub;        // 0..32767
    int dir = rid >> 14;
    int row = rid & (NROWS - 1);
    int c = tt * 8;
    const size_t base = (size_t)(dir * NROWS + row) * DINNER + c;
    uint4 yu = *(const uint4*)&Y[base];
    uint4 zu = *(const uint4*)&ZG[base];
    float v[8];
    {
        const unsigned int yw[4] = {yu.x, yu.y, yu.z, yu.w};
        const unsigned int zw[4] = {zu.x, zu.y, zu.z, zu.w};
#pragma unroll
        for (int e = 0; e < 4; e++) {
            v[e * 2]     = bf2f((unsigned short)(yw[e] & 0xffff)) * silu(bf2f((unsigned short)(zw[e] & 0xffff)));
            v[e * 2 + 1] = bf2f((unsigned short)(yw[e] >> 16))    * silu(bf2f((unsigned short)(zw[e] >> 16)));
        }
    }
    float ss = 0.f;
#pragma unroll
    for (int e = 0; e < 8; e++) ss += v[e] * v[e];
#pragma unroll
    for (int off = 32; off > 0; off >>= 1) ss += __shfl_down(ss, off);
    __shared__ float red[4];
    if ((t & 63) == 0) red[t >> 6] = ss;
    __syncthreads();
    float tot = red[sub * 2] + red[sub * 2 + 1];
    float scale = rsqrtf(tot * (1.f / 1024.f) + 1e-5f);
    const float* nw = (dir ? bnw : fnw) + c;
    f32x4 nw0 = *(const f32x4*)&nw[0];
    f32x4 nw1 = *(const f32x4*)&nw[4];
    unsigned int ow[4];
#pragma unroll
    for (int e = 0; e < 4; e++) {
        float a = v[e * 2]     * scale * (e < 2 ? nw0[e * 2]     : nw1[(e - 2) * 2]);
        float b = v[e * 2 + 1] * scale * (e < 2 ? nw0[e * 2 + 1] : nw1[(e - 2) * 2 + 1]);
        ow[e] = (unsigned int)f2bf(a) | ((unsigned int)f2bf(b) << 16);
    }
    uint4 o = {ow[0], ow[1], ow[2], ow[3]};
    *(uint4*)&NRM[(size_t)row * 2048 + dir * DINNER + c] = o;
}

// ---------------- host launch ----------------
extern "C" void kernel_launch(void* const* d_in, const int* in_sizes, int n_in,
                              void* d_out, int out_size, void* d_ws, size_t ws_size,
                              hipStream_t stream) {
    const float* x     = (const float*)d_in[0];
    const float* f_inw = (const float*)d_in[1];
    const float* f_cw  = (const float*)d_in[2];
    const float* f_cb  = (const float*)d_in[3];
    const float* f_dtb = (const float*)d_in[4];
    const float* f_Al  = (const float*)d_in[5];
    const float* f_Dp  = (const float*)d_in[6];
    const float* f_nw  = (const float*)d_in[7];
    const float* f_ow  = (const float*)d_in[8];
    const float* b_inw = (const float*)d_in[9];
    const float* b_cw  = (const float*)d_in[10];
    const float* b_cb  = (const float*)d_in[11];
    const float* b_dtb = (const float*)d_in[12];
    const float* b_Al  = (const float*)d_in[13];
    const float* b_Dp  = (const float*)d_in[14];
    const float* b_nw  = (const float*)d_in[15];
    const float* b_ow  = (const float*)d_in[16];

    char* ws = (char*)d_ws;
    size_t off = 0;
    auto alloc = [&](size_t bytes) {
        void* p = ws + off;
        off += (bytes + 255) & ~(size_t)255;
        return p;
    };
    // --- persistent-phase buffers ---
    // union: XBCDT (in_proj -> conv/dt) / {S,P} (phase 4) / NRM (gatenorm -> out GEMM)
    unsigned short* XBCDT = (unsigned short*)alloc((size_t)2 * NROWS * XBCW * 2);   // 70.3 MB
    unsigned short* NRM   = XBCDT;  // 67.1 MB <= 70.3 MB
    float* S = (float*)XBCDT;       // 2*8*16*NCH*1024*4 = 33.6 MB
    float* P = (float*)((char*)XBCDT + (size_t)2 * 8 * 16 * NCH * 1024 * 4);  // 32 KB
    // union: XS (conv -> scans) / Y (scan C writes over XS element-after-read)
    unsigned short* XS    = (unsigned short*)alloc((size_t)2 * NROWS * DINNER * 2); // 67.1 MB
    unsigned short* Yb    = XS;
    unsigned short* ZG    = (unsigned short*)alloc((size_t)2 * NROWS * DINNER * 2); // 67.1 MB
    unsigned short* W2    = (unsigned short*)alloc((size_t)512 * 2048 * 2);         //  2.1 MB
    float* BCb  = (float*)alloc((size_t)2 * NROWS * 32 * 4);                        //  4.2 MB
    float* DT   = (float*)alloc((size_t)2 * NROWS * NHEADS * 4);                    //  2.1 MB
    float* DA   = (float*)alloc((size_t)2 * NROWS * NHEADS * 4);                    //  2.1 MB
    // union: {XB, W1} (phase 0-1 only)
    char* unionBase = (char*)alloc((size_t)16777216 + (size_t)NPROJ_P * DMODEL * 2); // 21.1 MB
    unsigned short* XB = (unsigned short*)unionBase;
    unsigned short* W1 = (unsigned short*)(unionBase + 16777216);
    // total: ~236 MB

    if (ws_size < off) return;  // defensive: fail cleanly (wrong answer) instead of faulting

    // 1. merged prepack (vectorized)
    k_prep<<<(PREP_T + 255) / 256, 256, 0, stream>>>(x, f_inw, b_inw, f_ow, b_ow, XB, W1, W2);
    // 2. in_proj GEMM: triple-buffered counted-vmcnt pipeline (T4), routed epilogue
    k_gemm_proj<<<8 * 16 * 33, 256, 0, stream>>>(XB, W1, ZG, XBCDT);
    // 3. LDS-tiled conv + dt prep
    k_conv2<<<5 * 2 * 8 * 32, 256, 0, stream>>>(XBCDT, f_cw, f_cb, b_cw, b_cb, XS, BCb);
    {
        int n = 2 * NROWS * NHEADS;
        k_dt<<<(n + 255) / 256, 256, 0, stream>>>(XBCDT, f_dtb, f_Al, b_dtb, b_Al, DT, DA);
    }
    // 4. chunked scan, NCH=32 (S/P written over dead XBCDT region; combine in-place)
    k_scan_state<<<2 * 8 * 8 * NCH, 64, 0, stream>>>(XS, BCb, DT, DA, S, P);
    {
        int n = 2 * 8 * 16 * 1024;
        k_combine<<<(n + 255) / 256, 256, 0, stream>>>(S, P);
    }
    k_scan_out<<<2 * 8 * 8 * NCH, 64, 0, stream>>>(XS, BCb, DT, DA, S, f_Dp, b_Dp, Yb);
    // 5. gated RMSNorm -> bf16 (writes NRM over dead XBCDT/S region)
    k_gatenorm<<<NROWS, 256, 0, stream>>>(Yb, ZG, f_nw, b_nw, NRM);
    // 6. out_proj GEMM (both dirs summed via K-concat), XCD-swizzled -> d_out
    k_gemm_out<<<8 * 16 * 4, 256, 0, stream>>>(NRM, W2, (float*)d_out);
}